// Round 3
// baseline (443.393 us; speedup 1.0000x reference)
//
#include <hip/hip_runtime.h>
#include <hip/hip_bf16.h>

// MolecularGraphNet: 3x SAGEConv(mean) + Linear, on MI355X.
//  - GEMM operands in chunk-linear swizzled format:
//      elem(r,k) of [rows,K] at (r>>7)*(K*128) + (k>>3)*1024 + (r&127)*8 + (k&7)
//    => one K64-stage of a 128-row tile is a contiguous 16 KB block (global_load_lds).
//  - GEMM: 128x128 tile, BK=64 (16 barrier-pairs at K=1024), XCD-aware remap,
//    dual-store epilogue (swizzled for next GEMM + row-major for agg gather).
//  - Aggregation: wave-per-node, lanes partition FEATURES (no LDS, no syncthreads),
//    unroll-4 gather (4 rows in flight/wave) -- the gather is L2/L3-latency-bound,
//    not HBM-bound (h fits Infinity Cache).
//  - Dispatch count minimized (15 -> 11): single-WG scan; count+x2bf+transposes
//    fused into one block-range prep kernel. The whole net is a serial chain, so
//    every removed launch gap is pure win.

typedef __bf16 bf16x8 __attribute__((ext_vector_type(8)));
typedef float  f32x4  __attribute__((ext_vector_type(4)));

#define N_NODES 20000
#define N_EDGES 320000
#define MPAD 20096   // 157*128

__device__ __forceinline__ int clampi(int v, int lo, int hi) {
    return v < lo ? lo : (v > hi ? hi : v);
}

__device__ __forceinline__ void load16_lds(const void* g, void* l) {
    __builtin_amdgcn_global_load_lds(
        (const __attribute__((address_space(1))) void*)g,
        (__attribute__((address_space(3))) void*)l, 16, 0, 0);
}

// ---------------- fused prep: weight transposes + x->bf16 + edge count ----------------
// blocks [0,2304): transpose W fp32 [K,N] -> swizzled bf16 [N,KT]
// blocks [2304,4804): x -> bf16 row-major copy + swizzled x-chunks of Acat1
// blocks [4804,6054): edge dst histogram (cnt must be pre-zeroed)

struct TDesc { const float* W; __bf16* Wt; int K, N, KT, koff, tile0; };
struct TDescs { TDesc d[7]; };

__global__ void k_prep(TDescs ds, const float* __restrict__ x,
                       __bf16* __restrict__ xrm, __bf16* __restrict__ acat,
                       const int* __restrict__ ei, int* __restrict__ cnt) {
    __shared__ float tile[32][33];
    int b = blockIdx.x;
    int tid = threadIdx.y * 32 + threadIdx.x;

    if (b < 2304) {                       // ---- weight transpose ----
        int di = 0;
#pragma unroll
        for (int i = 1; i < 7; ++i)
            if (b >= ds.d[i].tile0) di = i;
        const float* W = ds.d[di].W;
        __bf16* Wt = ds.d[di].Wt;
        int N = ds.d[di].N, KT = ds.d[di].KT, koff = ds.d[di].koff;
        int t = b - ds.d[di].tile0;
        int ntn = N >> 5;
        int nb = (t % ntn) * 32, kb = (t / ntn) * 32;
        for (int i = 0; i < 32; i += 8) {
            int k = kb + threadIdx.y + i, n = nb + threadIdx.x;
            tile[threadIdx.y + i][threadIdx.x] = W[(size_t)k * N + n];
        }
        __syncthreads();
        for (int i = 0; i < 32; i += 8) {
            int n = nb + threadIdx.y + i, k = koff + kb + threadIdx.x;
            size_t o = (size_t)(n >> 7) * ((size_t)KT * 128) + (size_t)(k >> 3) * 1024 +
                       (size_t)((n & 127) * 8) + (k & 7);
            Wt[o] = (__bf16)tile[threadIdx.x][threadIdx.y + i];
        }
    } else if (b < 4804) {                // ---- x -> bf16 ----
        int node = (b - 2304) * 8 + (tid >> 5);   // 8 nodes/block -> whole 64B lines
        int f0 = (tid & 31) * 8;
        float4 u = *(const float4*)(x + (size_t)node * 256 + f0);
        float4 w = *(const float4*)(x + (size_t)node * 256 + f0 + 4);
        alignas(16) __bf16 tmp[8] = {(__bf16)u.x, (__bf16)u.y, (__bf16)u.z, (__bf16)u.w,
                                     (__bf16)w.x, (__bf16)w.y, (__bf16)w.z, (__bf16)w.w};
        *(uint4*)(xrm + (size_t)node * 256 + f0) = *(const uint4*)tmp;
        *(uint4*)(acat + (size_t)(node >> 7) * (512 * 128) +
                  (size_t)(32 + (f0 >> 3)) * 1024 + (size_t)((node & 127) * 8)) =
            *(const uint4*)tmp;
    } else {                              // ---- edge count ----
        int e = (b - 4804) * 256 + tid;   // exactly covers E = 320000
        atomicAdd(&cnt[clampi(ei[N_EDGES + e], 0, N_NODES - 1)], 1);
    }
}

// ---------------- single-workgroup exclusive scan (n = 20000) ----------------

__global__ __launch_bounds__(1024) void k_scan(const int* __restrict__ cnt,
                                               int* __restrict__ off,
                                               int* __restrict__ cur, int n) {
    __shared__ int sm[1024];
    __shared__ int carry;
    int tid = threadIdx.x;
    if (tid == 0) carry = 0;
    __syncthreads();
    for (int base = 0; base < n; base += 1024) {
        int i = base + tid;
        int v = (i < n) ? cnt[i] : 0;
        sm[tid] = v;
        __syncthreads();
        for (int s = 1; s < 1024; s <<= 1) {
            int t = (tid >= s) ? sm[tid - s] : 0;
            __syncthreads();
            sm[tid] += t;
            __syncthreads();
        }
        int exc = carry + sm[tid] - v;    // carry read before update barrier
        if (i < n) { off[i] = exc; cur[i] = exc; }
        __syncthreads();
        if (tid == 1023) carry += sm[1023];
        __syncthreads();
    }
    if (tid == 0) off[n] = carry;
}

__global__ void k_fill(const int* __restrict__ ei, int E,
                       int* __restrict__ cur, int* __restrict__ csr) {
    int e = blockIdx.x * blockDim.x + threadIdx.x;
    if (e < E) {
        int dst = clampi(ei[E + e], 0, N_NODES - 1);
        int src = clampi(ei[e], 0, N_NODES - 1);
        int pos = atomicAdd(&cur[dst], 1);
        if (pos >= 0 && pos < E) csr[pos] = src;
    }
}

// ---------------- aggregation (CSR gather, mean) ----------------
// Wave-per-node; lanes partition features (no LDS / no sync).
// D = row width in bf16 (256 for layer 1, 512 for layers 2/3).
// KC = swizzled Acat K width. Mean goes to chunks 0..D/8-1.
// Unroll-4 with hoisted loads: 4 gather rows in flight per wave.

template <int D, int KC>
__global__ __launch_bounds__(256) void k_agg(const __hip_bfloat16* __restrict__ hrm,
                                             const int* __restrict__ off,
                                             const int* __restrict__ csr,
                                             __bf16* __restrict__ acat) {
    constexpr int FPL = D / 64;   // features per lane: 4 (8B ld) or 8 (16B ld)
    int wave = threadIdx.x >> 6, lane = threadIdx.x & 63;
    int node = blockIdx.x * 4 + wave;
    int c0 = lane * FPL;
    int beg = off[node], end = off[node + 1];
    float a[FPL] = {};

    if constexpr (FPL == 8) {
        auto ldrow = [&](int s) { return *(const uint4*)(hrm + (size_t)s * D + c0); };
        auto addv = [&](uint4 v) {
            const __hip_bfloat16* hb = (const __hip_bfloat16*)&v;
#pragma unroll
            for (int j = 0; j < 8; ++j) a[j] += __bfloat162float(hb[j]);
        };
        int e = beg;
        for (; e + 3 < end; e += 4) {
            int s0 = csr[e], s1 = csr[e + 1], s2 = csr[e + 2], s3 = csr[e + 3];
            uint4 v0 = ldrow(s0), v1 = ldrow(s1), v2 = ldrow(s2), v3 = ldrow(s3);
            addv(v0); addv(v1); addv(v2); addv(v3);
        }
        for (; e < end; ++e) addv(ldrow(csr[e]));
    } else {
        auto ldrow = [&](int s) { return *(const uint2*)(hrm + (size_t)s * D + c0); };
        auto addv = [&](uint2 v) {
            const __hip_bfloat16* hb = (const __hip_bfloat16*)&v;
#pragma unroll
            for (int j = 0; j < 4; ++j) a[j] += __bfloat162float(hb[j]);
        };
        int e = beg;
        for (; e + 3 < end; e += 4) {
            int s0 = csr[e], s1 = csr[e + 1], s2 = csr[e + 2], s3 = csr[e + 3];
            uint2 v0 = ldrow(s0), v1 = ldrow(s1), v2 = ldrow(s2), v3 = ldrow(s3);
            addv(v0); addv(v1); addv(v2); addv(v3);
        }
        for (; e < end; ++e) addv(ldrow(csr[e]));
    }

    float inv = 1.f / fmaxf((float)(end - beg), 1.f);
    alignas(16) __bf16 tmp[FPL];
#pragma unroll
    for (int j = 0; j < FPL; ++j) tmp[j] = (__bf16)(a[j] * inv);

    __bf16* base = acat + (size_t)(node >> 7) * ((size_t)KC * 128) +
                   (size_t)((node & 127) * 8);
    if constexpr (FPL == 8) {
        *(uint4*)(base + (size_t)lane * 1024) = *(const uint4*)tmp;
    } else {
        *(uint2*)(base + (size_t)(lane >> 1) * 1024 + (size_t)((lane & 1) * 4)) =
            *(const uint2*)tmp;
    }
}

// ---------------- bf16 MFMA GEMM, swizzled operands ----------------
// OUTMODE: 0 = bf16 swizzled; 1 = bf16 swizzled + row-major copy; 2 = fp32 row-major.

template <bool RELU, int OUTMODE>
__global__ __launch_bounds__(256) void k_gemm(const __bf16* __restrict__ A, int K, int M,
                                              const __bf16* __restrict__ B,
                                              const float* __restrict__ bias,
                                              __bf16* __restrict__ osw, int Kc, int coff,
                                              __bf16* __restrict__ orm, int ldrm,
                                              float* __restrict__ of32, int ldf,
                                              int rtiles, int ctlog2) {
    constexpr int SMEM = (OUTMODE == 2) ? 34816 : 32768;
    __shared__ char smem[SMEM];
    __bf16* Alds = (__bf16*)smem;             // [2 sub-panels][4 chunks][128 rows][8]
    __bf16* Blds = (__bf16*)(smem + 16384);

    int bid = blockIdx.x;
    int xcd = bid & 7, local = bid >> 3;
    int cmask = (1 << ctlog2) - 1;
    int colTile = local & cmask;
    int rowTile = (local >> ctlog2) * 8 + xcd;
    if (rowTile >= rtiles) return;

    const __bf16* Atile = A + (size_t)rowTile * ((size_t)K * 128);
    const __bf16* Btile = B + (size_t)colTile * ((size_t)K * 128);

    int tid = threadIdx.x;
    int wave = tid >> 6, lane = tid & 63;
    int wr = wave >> 1, wc = wave & 1;
    int quad = lane >> 4, l16 = lane & 15;

    f32x4 acc[4][4] = {};

    for (int k0 = 0; k0 < K; k0 += 64) {
        __syncthreads();
        const __bf16* gA = Atile + (size_t)k0 * 128;   // contiguous 16 KB stage
        const __bf16* gB = Btile + (size_t)k0 * 128;
#pragma unroll
        for (int j = 0; j < 4; ++j) {
            int slot = (j * 256 + tid) * 8;
            load16_lds(gA + slot, Alds + slot);
            load16_lds(gB + slot, Blds + slot);
        }
        __syncthreads();
#pragma unroll
        for (int sp = 0; sp < 2; ++sp) {
            bf16x8 af[4], bf[4];
#pragma unroll
            for (int mi = 0; mi < 4; ++mi)
                af[mi] = *(const bf16x8*)(Alds + sp * 4096 + quad * 1024 +
                                          (wr * 64 + mi * 16 + l16) * 8);
#pragma unroll
            for (int ni = 0; ni < 4; ++ni)
                bf[ni] = *(const bf16x8*)(Blds + sp * 4096 + quad * 1024 +
                                          (wc * 64 + ni * 16 + l16) * 8);
#pragma unroll
            for (int mi = 0; mi < 4; ++mi)
#pragma unroll
                for (int ni = 0; ni < 4; ++ni)
                    acc[mi][ni] = __builtin_amdgcn_mfma_f32_16x16x32_bf16(
                        af[mi], bf[ni], acc[mi][ni], 0, 0, 0);
        }
    }

    int col0 = colTile * 128;
    int row0 = rowTile * 128;
    __syncthreads();   // frag reads done; smem free for epilogue

    if (OUTMODE != 2) {
        // stage C chunk-major [16 chunks][128 rows][8] = 32 KB
        __bf16* cb = (__bf16*)smem;
#pragma unroll
        for (int ni = 0; ni < 4; ++ni) {
            int ct = wc * 64 + ni * 16 + l16;
            float bv = bias[col0 + ct];
#pragma unroll
            for (int mi = 0; mi < 4; ++mi) {
                int rb = wr * 64 + mi * 16 + quad * 4;
#pragma unroll
                for (int r = 0; r < 4; ++r) {
                    float v = acc[mi][ni][r] + bv;
                    if (RELU) v = fmaxf(v, 0.f);
                    cb[(ct >> 3) * 1024 + (rb + r) * 8 + (ct & 7)] = (__bf16)v;
                }
            }
        }
        __syncthreads();
        // swizzled store: one contiguous 32 KB region (padded rows -> no guard)
        __bf16* dst = osw + (size_t)rowTile * ((size_t)Kc * 128) +
                      (size_t)((coff + col0) >> 3) * 1024;
#pragma unroll
        for (int p2 = 0; p2 < 8; ++p2) {
            int idx = (p2 * 256 + tid) * 8;
            *(uint4*)(dst + idx) = *(const uint4*)(cb + idx);
        }
        if (OUTMODE == 1) {
            // row-major copy for the aggregation gather (padded rows -> no guard)
#pragma unroll
            for (int p2 = 0; p2 < 8; ++p2) {
                int rr = p2 * 16 + (tid >> 4);
                int cc = tid & 15;
                *(uint4*)(orm + (size_t)(row0 + rr) * ldrm + col0 + cc * 8) =
                    *(const uint4*)(cb + cc * 1024 + rr * 8);
            }
        }
    } else {
        float* cf = (float*)smem;   // [128][68] fp32, two 64-col halves
#pragma unroll
        for (int h = 0; h < 2; ++h) {
            if (wc == h) {
#pragma unroll
                for (int ni = 0; ni < 4; ++ni) {
                    int ctl = ni * 16 + l16;
                    float bv = bias[col0 + h * 64 + ctl];
#pragma unroll
                    for (int mi = 0; mi < 4; ++mi) {
                        int rb = wr * 64 + mi * 16 + quad * 4;
#pragma unroll
                        for (int r = 0; r < 4; ++r) {
                            float v = acc[mi][ni][r] + bv;
                            if (RELU) v = fmaxf(v, 0.f);
                            cf[(rb + r) * 68 + ctl] = v;
                        }
                    }
                }
            }
            __syncthreads();
            int chunk = tid & 15, rl = tid >> 4;
#pragma unroll
            for (int p2 = 0; p2 < 8; ++p2) {
                int rt = p2 * 16 + rl;
                int row = row0 + rt;
                if (row < M) {
                    float4 v = *(const float4*)(cf + rt * 68 + chunk * 4);
                    *(float4*)(of32 + (size_t)row * ldf + col0 + h * 64 + chunk * 4) = v;
                }
            }
            __syncthreads();
        }
    }
}

// ---------------- launch ----------------

extern "C" void kernel_launch(void* const* d_in, const int* in_sizes, int n_in,
                              void* d_out, int out_size, void* d_ws, size_t ws_size,
                              hipStream_t stream) {
    const float* x   = (const float*)d_in[0];
    const int*   ei  = (const int*)d_in[1];
    const float* Wl1 = (const float*)d_in[2];
    const float* bl1 = (const float*)d_in[3];
    const float* Wr1 = (const float*)d_in[4];
    const float* Wl2 = (const float*)d_in[5];
    const float* bl2 = (const float*)d_in[6];
    const float* Wr2 = (const float*)d_in[7];
    const float* Wl3 = (const float*)d_in[8];
    const float* bl3 = (const float*)d_in[9];
    const float* Wr3 = (const float*)d_in[10];
    const float* Wfc = (const float*)d_in[11];
    const float* bfc = (const float*)d_in[12];
    float* out = (float*)d_out;

    const int NN = N_NODES, E = N_EDGES;

    char* p = (char*)d_ws;
    auto alloc = [&](size_t bytes) {
        char* r = p;
        p += (bytes + 511) & ~(size_t)511;
        return r;
    };
    int* cnt   = (int*)alloc((size_t)NN * 4);
    int* off   = (int*)alloc((size_t)(NN + 1) * 4);
    int* cur   = (int*)alloc((size_t)NN * 4);
    int* csr   = (int*)alloc((size_t)E * 4);
    __bf16* Acat1 = (__bf16*)alloc((size_t)MPAD * 512 * 2);    // swz [mean|x], K=512
    __bf16* Acat2 = (__bf16*)alloc((size_t)MPAD * 1024 * 2);   // swz [mean|h1], K=1024
    __bf16* Acat3 = (__bf16*)alloc((size_t)MPAD * 1024 * 2);   // swz [mean|h2], K=1024
    __bf16* Hrm   = (__bf16*)alloc((size_t)MPAD * 512 * 2);    // row-major h1, then h2
    __bf16* Xrm   = (__bf16*)alloc((size_t)MPAD * 256 * 2);    // row-major bf16 x
    __bf16* Wt1 = (__bf16*)alloc((size_t)512 * 512 * 2);
    __bf16* Wt2 = (__bf16*)alloc((size_t)512 * 1024 * 2);
    __bf16* Wt3 = (__bf16*)alloc((size_t)1024 * 1024 * 2);
    __bf16* Wt4 = (__bf16*)alloc((size_t)512 * 1024 * 2);
    __bf16* H3 = Acat2;   // alias: Acat2 dead after GEMM2 reads it

    // prep: weight transposes + x->bf16 + edge count (after cnt zeroing)
    hipMemsetAsync(cnt, 0, (size_t)NN * 4, stream);
    TDescs td;
    td.d[0] = {Wl1, Wt1, 256, 512, 512, 0, 0};
    td.d[1] = {Wr1, Wt1, 256, 512, 512, 256, 128};
    td.d[2] = {Wl2, Wt2, 512, 512, 1024, 0, 256};
    td.d[3] = {Wr2, Wt2, 512, 512, 1024, 512, 512};
    td.d[4] = {Wl3, Wt3, 512, 1024, 1024, 0, 768};
    td.d[5] = {Wr3, Wt3, 512, 1024, 1024, 512, 1280};
    td.d[6] = {Wfc, Wt4, 1024, 512, 1024, 0, 1792};
    k_prep<<<6054, dim3(32, 8), 0, stream>>>(td, x, Xrm, Acat1, ei, cnt);

    k_scan<<<1, 1024, 0, stream>>>(cnt, off, cur, NN);
    k_fill<<<(E + 255) / 256, 256, 0, stream>>>(ei, E, cur, csr);

    int rtiles = (NN + 127) / 128;        // 157
    int rg = ((rtiles + 7) / 8) * 8;      // 160

    // Layer 1 (bf16 gather @ 512 B/row)
    k_agg<256, 512><<<NN / 4, 256, 0, stream>>>(
        (const __hip_bfloat16*)Xrm, off, csr, Acat1);
    k_gemm<true, 1><<<rg * 4, 256, 0, stream>>>(
        Acat1, 512, NN, Wt1, bl1, Acat2, 1024, 512, Hrm, 512, nullptr, 0, rtiles, 2);

    // Layer 2
    k_agg<512, 1024><<<NN / 4, 256, 0, stream>>>(
        (const __hip_bfloat16*)Hrm, off, csr, Acat2);
    k_gemm<true, 1><<<rg * 4, 256, 0, stream>>>(
        Acat2, 1024, NN, Wt2, bl2, Acat3, 1024, 512, Hrm, 512, nullptr, 0, rtiles, 2);

    // Layer 3 (writes H3 == Acat2 swizzled only; FC reads it swizzled)
    k_agg<512, 1024><<<NN / 4, 256, 0, stream>>>(
        (const __hip_bfloat16*)Hrm, off, csr, Acat3);
    k_gemm<true, 0><<<rg * 8, 256, 0, stream>>>(
        Acat3, 1024, NN, Wt3, bl3, H3, 1024, 0, nullptr, 0, nullptr, 0, rtiles, 3);

    // FC (fp32 row-major out, no relu)
    k_gemm<false, 2><<<rg * 4, 256, 0, stream>>>(
        H3, 1024, NN, Wt4, bfc, nullptr, 0, 0, nullptr, 0, out, 512, rtiles, 2);
}

// Round 4
// 404.450 us; speedup vs baseline: 1.0963x; 1.0963x over previous
//
#include <hip/hip_runtime.h>
#include <hip/hip_bf16.h>

// MolecularGraphNet: 3x SAGEConv(mean) + Linear, on MI355X.
//  - GEMM operands in chunk-linear swizzled format:
//      elem(r,k) of [rows,K] at (r>>7)*(K*128) + (k>>3)*1024 + (r&127)*8 + (k&7)
//    => one K64-stage of a 128-row tile is a contiguous 16 KB block (global_load_lds).
//  - GEMM: 128x128 tile, BK=64, DOUBLE-BUFFERED staging (T3 2-phase): stage(t+1)
//    issued before compute(t), one __syncthreads per K-step (its vmcnt(0) drain
//    lands after staging latency is hidden under MFMA). 64 KB LDS -> 2 blocks/CU.
//  - Aggregation: wave-per-node, lanes partition FEATURES (no LDS, no syncthreads),
//    unroll-4 gather; gather is L2/L3-latency-bound (h fits Infinity Cache).
//  - Prep fusion (parallel-safe only): weight transposes + x->bf16 + edge count in
//    one dispatch. Scan stays the PARALLEL 3-kernel version (single-WG scan was a
//    26 us regression in round 3 -- it serialized 20 CUs of work onto one).

typedef __bf16 bf16x8 __attribute__((ext_vector_type(8)));
typedef float  f32x4  __attribute__((ext_vector_type(4)));

#define N_NODES 20000
#define N_EDGES 320000
#define MPAD 20096   // 157*128

__device__ __forceinline__ int clampi(int v, int lo, int hi) {
    return v < lo ? lo : (v > hi ? hi : v);
}

__device__ __forceinline__ void load16_lds(const void* g, void* l) {
    __builtin_amdgcn_global_load_lds(
        (const __attribute__((address_space(1))) void*)g,
        (__attribute__((address_space(3))) void*)l, 16, 0, 0);
}

// ---------------- fused prep: weight transposes + x->bf16 + edge count ----------------
// blocks [0,2304): transpose W fp32 [K,N] -> swizzled bf16 [N,KT]
// blocks [2304,4804): x -> bf16 row-major copy + swizzled x-chunks of Acat1
// blocks [4804,6054): edge dst histogram (cnt must be pre-zeroed)

struct TDesc { const float* W; __bf16* Wt; int K, N, KT, koff, tile0; };
struct TDescs { TDesc d[7]; };

__global__ void k_prep(TDescs ds, const float* __restrict__ x,
                       __bf16* __restrict__ xrm, __bf16* __restrict__ acat,
                       const int* __restrict__ ei, int* __restrict__ cnt) {
    __shared__ float tile[32][33];
    int b = blockIdx.x;
    int tid = threadIdx.y * 32 + threadIdx.x;

    if (b < 2304) {                       // ---- weight transpose ----
        int di = 0;
#pragma unroll
        for (int i = 1; i < 7; ++i)
            if (b >= ds.d[i].tile0) di = i;
        const float* W = ds.d[di].W;
        __bf16* Wt = ds.d[di].Wt;
        int N = ds.d[di].N, KT = ds.d[di].KT, koff = ds.d[di].koff;
        int t = b - ds.d[di].tile0;
        int ntn = N >> 5;
        int nb = (t % ntn) * 32, kb = (t / ntn) * 32;
        for (int i = 0; i < 32; i += 8) {
            int k = kb + threadIdx.y + i, n = nb + threadIdx.x;
            tile[threadIdx.y + i][threadIdx.x] = W[(size_t)k * N + n];
        }
        __syncthreads();
        for (int i = 0; i < 32; i += 8) {
            int n = nb + threadIdx.y + i, k = koff + kb + threadIdx.x;
            size_t o = (size_t)(n >> 7) * ((size_t)KT * 128) + (size_t)(k >> 3) * 1024 +
                       (size_t)((n & 127) * 8) + (k & 7);
            Wt[o] = (__bf16)tile[threadIdx.x][threadIdx.y + i];
        }
    } else if (b < 4804) {                // ---- x -> bf16 ----
        int node = (b - 2304) * 8 + (tid >> 5);   // 8 nodes/block -> whole 64B lines
        int f0 = (tid & 31) * 8;
        float4 u = *(const float4*)(x + (size_t)node * 256 + f0);
        float4 w = *(const float4*)(x + (size_t)node * 256 + f0 + 4);
        alignas(16) __bf16 tmp[8] = {(__bf16)u.x, (__bf16)u.y, (__bf16)u.z, (__bf16)u.w,
                                     (__bf16)w.x, (__bf16)w.y, (__bf16)w.z, (__bf16)w.w};
        *(uint4*)(xrm + (size_t)node * 256 + f0) = *(const uint4*)tmp;
        *(uint4*)(acat + (size_t)(node >> 7) * (512 * 128) +
                  (size_t)(32 + (f0 >> 3)) * 1024 + (size_t)((node & 127) * 8)) =
            *(const uint4*)tmp;
    } else {                              // ---- edge count ----
        int e = (b - 4804) * 256 + tid;   // exactly covers E = 320000
        atomicAdd(&cnt[clampi(ei[N_EDGES + e], 0, N_NODES - 1)], 1);
    }
}

// ---------------- parallel scan (3 kernels, 20 blocks) ----------------

__global__ __launch_bounds__(1024) void k_scan_block(const int* __restrict__ cnt,
                                                     int* __restrict__ off,
                                                     int* __restrict__ bsum, int n) {
    __shared__ int sm[1024];
    int b = blockIdx.x, tid = threadIdx.x;
    int i = b * 1024 + tid;
    int v = (i < n) ? cnt[i] : 0;
    sm[tid] = v;
    __syncthreads();
    for (int s = 1; s < 1024; s <<= 1) {
        int t = (tid >= s) ? sm[tid - s] : 0;
        __syncthreads();
        sm[tid] += t;
        __syncthreads();
    }
    if (i < n) off[i] = sm[tid] - v;
    if (tid == 1023) bsum[b] = sm[1023];
}

__global__ void k_scan_carry(const int* __restrict__ bsum, int* __restrict__ carry,
                             int nb, int* __restrict__ off, int n) {
    if (threadIdx.x == 0 && blockIdx.x == 0) {
        int acc = 0;
        for (int b = 0; b < nb; ++b) { carry[b] = acc; acc += bsum[b]; }
        off[n] = acc;
    }
}

__global__ __launch_bounds__(1024) void k_scan_add(int* __restrict__ off,
                                                   int* __restrict__ cur,
                                                   const int* __restrict__ carry, int n) {
    int i = blockIdx.x * 1024 + threadIdx.x;
    if (i < n) {
        int v = off[i] + carry[blockIdx.x];
        off[i] = v;
        cur[i] = v;
    }
}

__global__ void k_fill(const int* __restrict__ ei, int E,
                       int* __restrict__ cur, int* __restrict__ csr) {
    int e = blockIdx.x * blockDim.x + threadIdx.x;
    if (e < E) {
        int dst = clampi(ei[E + e], 0, N_NODES - 1);
        int src = clampi(ei[e], 0, N_NODES - 1);
        int pos = atomicAdd(&cur[dst], 1);
        if (pos >= 0 && pos < E) csr[pos] = src;
    }
}

// ---------------- aggregation (CSR gather, mean) ----------------
// Wave-per-node; lanes partition features (no LDS / no sync).
// D = row width in bf16 (256 for layer 1, 512 for layers 2/3).
// KC = swizzled Acat K width. Mean goes to chunks 0..D/8-1.
// Unroll-4 with hoisted loads: 4 gather rows in flight per wave.

template <int D, int KC>
__global__ __launch_bounds__(256) void k_agg(const __hip_bfloat16* __restrict__ hrm,
                                             const int* __restrict__ off,
                                             const int* __restrict__ csr,
                                             __bf16* __restrict__ acat) {
    constexpr int FPL = D / 64;   // features per lane: 4 (8B ld) or 8 (16B ld)
    int wave = threadIdx.x >> 6, lane = threadIdx.x & 63;
    int node = blockIdx.x * 4 + wave;
    int c0 = lane * FPL;
    int beg = off[node], end = off[node + 1];
    float a[FPL] = {};

    if constexpr (FPL == 8) {
        auto ldrow = [&](int s) { return *(const uint4*)(hrm + (size_t)s * D + c0); };
        auto addv = [&](uint4 v) {
            const __hip_bfloat16* hb = (const __hip_bfloat16*)&v;
#pragma unroll
            for (int j = 0; j < 8; ++j) a[j] += __bfloat162float(hb[j]);
        };
        int e = beg;
        for (; e + 3 < end; e += 4) {
            int s0 = csr[e], s1 = csr[e + 1], s2 = csr[e + 2], s3 = csr[e + 3];
            uint4 v0 = ldrow(s0), v1 = ldrow(s1), v2 = ldrow(s2), v3 = ldrow(s3);
            addv(v0); addv(v1); addv(v2); addv(v3);
        }
        for (; e < end; ++e) addv(ldrow(csr[e]));
    } else {
        auto ldrow = [&](int s) { return *(const uint2*)(hrm + (size_t)s * D + c0); };
        auto addv = [&](uint2 v) {
            const __hip_bfloat16* hb = (const __hip_bfloat16*)&v;
#pragma unroll
            for (int j = 0; j < 4; ++j) a[j] += __bfloat162float(hb[j]);
        };
        int e = beg;
        for (; e + 3 < end; e += 4) {
            int s0 = csr[e], s1 = csr[e + 1], s2 = csr[e + 2], s3 = csr[e + 3];
            uint2 v0 = ldrow(s0), v1 = ldrow(s1), v2 = ldrow(s2), v3 = ldrow(s3);
            addv(v0); addv(v1); addv(v2); addv(v3);
        }
        for (; e < end; ++e) addv(ldrow(csr[e]));
    }

    float inv = 1.f / fmaxf((float)(end - beg), 1.f);
    alignas(16) __bf16 tmp[FPL];
#pragma unroll
    for (int j = 0; j < FPL; ++j) tmp[j] = (__bf16)(a[j] * inv);

    __bf16* base = acat + (size_t)(node >> 7) * ((size_t)KC * 128) +
                   (size_t)((node & 127) * 8);
    if constexpr (FPL == 8) {
        *(uint4*)(base + (size_t)lane * 1024) = *(const uint4*)tmp;
    } else {
        *(uint2*)(base + (size_t)(lane >> 1) * 1024 + (size_t)((lane & 1) * 4)) =
            *(const uint2*)tmp;
    }
}

// ---------------- bf16 MFMA GEMM, swizzled operands, double-buffered ----------------
// OUTMODE: 0 = bf16 swizzled; 1 = bf16 swizzled + row-major copy; 2 = fp32 row-major.

template <bool RELU, int OUTMODE>
__global__ __launch_bounds__(256) void k_gemm(const __bf16* __restrict__ A, int K, int M,
                                              const __bf16* __restrict__ B,
                                              const float* __restrict__ bias,
                                              __bf16* __restrict__ osw, int Kc, int coff,
                                              __bf16* __restrict__ orm, int ldrm,
                                              float* __restrict__ of32, int ldf,
                                              int rtiles, int ctlog2) {
    __shared__ char smem[65536];   // 2 x [A 16KB | B 16KB] double buffer

    int bid = blockIdx.x;
    int xcd = bid & 7, local = bid >> 3;
    int cmask = (1 << ctlog2) - 1;
    int colTile = local & cmask;
    int rowTile = (local >> ctlog2) * 8 + xcd;
    if (rowTile >= rtiles) return;

    const __bf16* Atile = A + (size_t)rowTile * ((size_t)K * 128);
    const __bf16* Btile = B + (size_t)colTile * ((size_t)K * 128);

    int tid = threadIdx.x;
    int wave = tid >> 6, lane = tid & 63;
    int wr = wave >> 1, wc = wave & 1;
    int quad = lane >> 4, l16 = lane & 15;

    f32x4 acc[4][4] = {};
    const int nt = K >> 6;

    auto stage = [&](int buf, int t) {
        const __bf16* gA = Atile + (size_t)t * 64 * 128;   // contiguous 16 KB
        const __bf16* gB = Btile + (size_t)t * 64 * 128;
        __bf16* Al = (__bf16*)(smem + buf * 32768);
        __bf16* Bl = Al + 8192;
#pragma unroll
        for (int j = 0; j < 4; ++j) {
            int slot = (j * 256 + tid) * 8;
            load16_lds(gA + slot, Al + slot);
            load16_lds(gB + slot, Bl + slot);
        }
    };

    stage(0, 0);
    __syncthreads();   // vmcnt(0) drain: buf0 ready
    int cur = 0;
    for (int t = 0; t < nt; ++t) {
        if (t + 1 < nt) stage(cur ^ 1, t + 1);   // prefetch overlaps compute
        const __bf16* Alds = (const __bf16*)(smem + cur * 32768);
        const __bf16* Blds = Alds + 8192;
#pragma unroll
        for (int sp = 0; sp < 2; ++sp) {
            bf16x8 af[4], bf[4];
#pragma unroll
            for (int mi = 0; mi < 4; ++mi)
                af[mi] = *(const bf16x8*)(Alds + sp * 4096 + quad * 1024 +
                                          (wr * 64 + mi * 16 + l16) * 8);
#pragma unroll
            for (int ni = 0; ni < 4; ++ni)
                bf[ni] = *(const bf16x8*)(Blds + sp * 4096 + quad * 1024 +
                                          (wc * 64 + ni * 16 + l16) * 8);
#pragma unroll
            for (int mi = 0; mi < 4; ++mi)
#pragma unroll
                for (int ni = 0; ni < 4; ++ni)
                    acc[mi][ni] = __builtin_amdgcn_mfma_f32_16x16x32_bf16(
                        af[mi], bf[ni], acc[mi][ni], 0, 0, 0);
        }
        __syncthreads();   // single barrier/K-step: drains next-tile loads (vmcnt 0)
        cur ^= 1;
    }

    int col0 = colTile * 128;
    int row0 = rowTile * 128;
    // last loop iteration ended with __syncthreads(): smem free for epilogue

    if (OUTMODE != 2) {
        // stage C chunk-major [16 chunks][128 rows][8] = 32 KB
        __bf16* cb = (__bf16*)smem;
#pragma unroll
        for (int ni = 0; ni < 4; ++ni) {
            int ct = wc * 64 + ni * 16 + l16;
            float bv = bias[col0 + ct];
#pragma unroll
            for (int mi = 0; mi < 4; ++mi) {
                int rb = wr * 64 + mi * 16 + quad * 4;
#pragma unroll
                for (int r = 0; r < 4; ++r) {
                    float v = acc[mi][ni][r] + bv;
                    if (RELU) v = fmaxf(v, 0.f);
                    cb[(ct >> 3) * 1024 + (rb + r) * 8 + (ct & 7)] = (__bf16)v;
                }
            }
        }
        __syncthreads();
        // swizzled store: one contiguous 32 KB region (padded rows -> no guard)
        __bf16* dst = osw + (size_t)rowTile * ((size_t)Kc * 128) +
                      (size_t)((coff + col0) >> 3) * 1024;
#pragma unroll
        for (int p2 = 0; p2 < 8; ++p2) {
            int idx = (p2 * 256 + tid) * 8;
            *(uint4*)(dst + idx) = *(const uint4*)(cb + idx);
        }
        if (OUTMODE == 1) {
            // row-major copy for the aggregation gather (padded rows -> no guard)
#pragma unroll
            for (int p2 = 0; p2 < 8; ++p2) {
                int rr = p2 * 16 + (tid >> 4);
                int cc = tid & 15;
                *(uint4*)(orm + (size_t)(row0 + rr) * ldrm + col0 + cc * 8) =
                    *(const uint4*)(cb + cc * 1024 + rr * 8);
            }
        }
    } else {
        float* cf = (float*)smem;   // [128][68] fp32, two 64-col halves
#pragma unroll
        for (int h = 0; h < 2; ++h) {
            if (wc == h) {
#pragma unroll
                for (int ni = 0; ni < 4; ++ni) {
                    int ctl = ni * 16 + l16;
                    float bv = bias[col0 + h * 64 + ctl];
#pragma unroll
                    for (int mi = 0; mi < 4; ++mi) {
                        int rb = wr * 64 + mi * 16 + quad * 4;
#pragma unroll
                        for (int r = 0; r < 4; ++r) {
                            float v = acc[mi][ni][r] + bv;
                            if (RELU) v = fmaxf(v, 0.f);
                            cf[(rb + r) * 68 + ctl] = v;
                        }
                    }
                }
            }
            __syncthreads();
            int chunk = tid & 15, rl = tid >> 4;
#pragma unroll
            for (int p2 = 0; p2 < 8; ++p2) {
                int rt = p2 * 16 + rl;
                int row = row0 + rt;
                if (row < M) {
                    float4 v = *(const float4*)(cf + rt * 68 + chunk * 4);
                    *(float4*)(of32 + (size_t)row * ldf + col0 + h * 64 + chunk * 4) = v;
                }
            }
            __syncthreads();
        }
    }
}

// ---------------- launch ----------------

extern "C" void kernel_launch(void* const* d_in, const int* in_sizes, int n_in,
                              void* d_out, int out_size, void* d_ws, size_t ws_size,
                              hipStream_t stream) {
    const float* x   = (const float*)d_in[0];
    const int*   ei  = (const int*)d_in[1];
    const float* Wl1 = (const float*)d_in[2];
    const float* bl1 = (const float*)d_in[3];
    const float* Wr1 = (const float*)d_in[4];
    const float* Wl2 = (const float*)d_in[5];
    const float* bl2 = (const float*)d_in[6];
    const float* Wr2 = (const float*)d_in[7];
    const float* Wl3 = (const float*)d_in[8];
    const float* bl3 = (const float*)d_in[9];
    const float* Wr3 = (const float*)d_in[10];
    const float* Wfc = (const float*)d_in[11];
    const float* bfc = (const float*)d_in[12];
    float* out = (float*)d_out;

    const int NN = N_NODES, E = N_EDGES;
    const int NB = (NN + 1023) / 1024;

    char* p = (char*)d_ws;
    auto alloc = [&](size_t bytes) {
        char* r = p;
        p += (bytes + 511) & ~(size_t)511;
        return r;
    };
    int* cnt   = (int*)alloc((size_t)NN * 4);
    int* off   = (int*)alloc((size_t)(NN + 1) * 4);
    int* cur   = (int*)alloc((size_t)NN * 4);
    int* csr   = (int*)alloc((size_t)E * 4);
    int* bsum  = (int*)alloc((size_t)NB * 4);
    int* carry = (int*)alloc((size_t)NB * 4);
    __bf16* Acat1 = (__bf16*)alloc((size_t)MPAD * 512 * 2);    // swz [mean|x], K=512
    __bf16* Acat2 = (__bf16*)alloc((size_t)MPAD * 1024 * 2);   // swz [mean|h1], K=1024
    __bf16* Acat3 = (__bf16*)alloc((size_t)MPAD * 1024 * 2);   // swz [mean|h2], K=1024
    __bf16* Hrm   = (__bf16*)alloc((size_t)MPAD * 512 * 2);    // row-major h1, then h2
    __bf16* Xrm   = (__bf16*)alloc((size_t)MPAD * 256 * 2);    // row-major bf16 x
    __bf16* Wt1 = (__bf16*)alloc((size_t)512 * 512 * 2);
    __bf16* Wt2 = (__bf16*)alloc((size_t)512 * 1024 * 2);
    __bf16* Wt3 = (__bf16*)alloc((size_t)1024 * 1024 * 2);
    __bf16* Wt4 = (__bf16*)alloc((size_t)512 * 1024 * 2);
    __bf16* H3 = Acat2;   // alias: Acat2 dead after GEMM2 reads it

    // prep: weight transposes + x->bf16 + edge count (after cnt zeroing)
    hipMemsetAsync(cnt, 0, (size_t)NN * 4, stream);
    TDescs td;
    td.d[0] = {Wl1, Wt1, 256, 512, 512, 0, 0};
    td.d[1] = {Wr1, Wt1, 256, 512, 512, 256, 128};
    td.d[2] = {Wl2, Wt2, 512, 512, 1024, 0, 256};
    td.d[3] = {Wr2, Wt2, 512, 512, 1024, 512, 512};
    td.d[4] = {Wl3, Wt3, 512, 1024, 1024, 0, 768};
    td.d[5] = {Wr3, Wt3, 512, 1024, 1024, 512, 1280};
    td.d[6] = {Wfc, Wt4, 1024, 512, 1024, 0, 1792};
    k_prep<<<6054, dim3(32, 8), 0, stream>>>(td, x, Xrm, Acat1, ei, cnt);

    // parallel scan + CSR fill
    k_scan_block<<<NB, 1024, 0, stream>>>(cnt, off, bsum, NN);
    k_scan_carry<<<1, 64, 0, stream>>>(bsum, carry, NB, off, NN);
    k_scan_add<<<NB, 1024, 0, stream>>>(off, cur, carry, NN);
    k_fill<<<(E + 255) / 256, 256, 0, stream>>>(ei, E, cur, csr);

    int rtiles = (NN + 127) / 128;        // 157
    int rg = ((rtiles + 7) / 8) * 8;      // 160

    // Layer 1 (bf16 gather @ 512 B/row)
    k_agg<256, 512><<<NN / 4, 256, 0, stream>>>(
        (const __hip_bfloat16*)Xrm, off, csr, Acat1);
    k_gemm<true, 1><<<rg * 4, 256, 0, stream>>>(
        Acat1, 512, NN, Wt1, bl1, Acat2, 1024, 512, Hrm, 512, nullptr, 0, rtiles, 2);

    // Layer 2
    k_agg<512, 1024><<<NN / 4, 256, 0, stream>>>(
        (const __hip_bfloat16*)Hrm, off, csr, Acat2);
    k_gemm<true, 1><<<rg * 4, 256, 0, stream>>>(
        Acat2, 1024, NN, Wt2, bl2, Acat3, 1024, 512, Hrm, 512, nullptr, 0, rtiles, 2);

    // Layer 3 (writes H3 == Acat2 swizzled only; FC reads it swizzled)
    k_agg<512, 1024><<<NN / 4, 256, 0, stream>>>(
        (const __hip_bfloat16*)Hrm, off, csr, Acat3);
    k_gemm<true, 0><<<rg * 8, 256, 0, stream>>>(
        Acat3, 1024, NN, Wt3, bl3, H3, 1024, 0, nullptr, 0, nullptr, 0, rtiles, 3);

    // FC (fp32 row-major out, no relu)
    k_gemm<false, 2><<<rg * 4, 256, 0, stream>>>(
        H3, 1024, NN, Wt4, bfc, nullptr, 0, 0, nullptr, 0, out, 512, rtiles, 2);
}

// Round 5
// 390.649 us; speedup vs baseline: 1.1350x; 1.0353x over previous
//
#include <hip/hip_runtime.h>
#include <hip/hip_bf16.h>

// MolecularGraphNet: 3x SAGEConv(mean) + Linear, on MI355X.
//  - GEMM operands in chunk-linear swizzled format:
//      elem(r,k) of [rows,K] at (r>>7)*(K*128) + (k>>3)*1024 + (r&127)*8 + (k&7)
//    => one K64-stage of a 128-row tile is a contiguous 16 KB block; a 64-row
//       half-panel is 8x 1KB blocks at 2KB stride (still wave-coalesced).
//  - GEMM: MT x 128 tile (MT=128 for the N=1024 GEMM3; MT=64 for the three N=512
//    GEMMs -> 1280 blocks instead of 640, 48KB dbuf -> 3 blocks/CU resident).
//    Round-4 lesson: these GEMMs are parallelism-bound (m97-structure ceiling),
//    so more resident blocks beats deeper intra-block pipelining.
//  - Double-buffered staging: stage(t+1) issued before compute(t), one
//    __syncthreads per K-step.
//  - Aggregation: wave-per-node, lanes partition features, unroll-4 gather.
//  - Prep fusion (parallel-safe only); scan stays the parallel 3-kernel version
//    (single-WG scan was a 26us regression in round 3).

typedef __bf16 bf16x8 __attribute__((ext_vector_type(8)));
typedef float  f32x4  __attribute__((ext_vector_type(4)));

#define N_NODES 20000
#define N_EDGES 320000
#define MPAD 20096   // 157*128 = 314*64

__device__ __forceinline__ int clampi(int v, int lo, int hi) {
    return v < lo ? lo : (v > hi ? hi : v);
}

__device__ __forceinline__ void load16_lds(const void* g, void* l) {
    __builtin_amdgcn_global_load_lds(
        (const __attribute__((address_space(1))) void*)g,
        (__attribute__((address_space(3))) void*)l, 16, 0, 0);
}

// ---------------- fused prep: weight transposes + x->bf16 + edge count ----------------
// blocks [0,2304): transpose W fp32 [K,N] -> swizzled bf16 [N,KT]
// blocks [2304,4804): x -> bf16 row-major copy + swizzled x-chunks of Acat1
// blocks [4804,6054): edge dst histogram (cnt must be pre-zeroed)

struct TDesc { const float* W; __bf16* Wt; int K, N, KT, koff, tile0; };
struct TDescs { TDesc d[7]; };

__global__ void k_prep(TDescs ds, const float* __restrict__ x,
                       __bf16* __restrict__ xrm, __bf16* __restrict__ acat,
                       const int* __restrict__ ei, int* __restrict__ cnt) {
    __shared__ float tile[32][33];
    int b = blockIdx.x;
    int tid = threadIdx.y * 32 + threadIdx.x;

    if (b < 2304) {                       // ---- weight transpose ----
        int di = 0;
#pragma unroll
        for (int i = 1; i < 7; ++i)
            if (b >= ds.d[i].tile0) di = i;
        const float* W = ds.d[di].W;
        __bf16* Wt = ds.d[di].Wt;
        int N = ds.d[di].N, KT = ds.d[di].KT, koff = ds.d[di].koff;
        int t = b - ds.d[di].tile0;
        int ntn = N >> 5;
        int nb = (t % ntn) * 32, kb = (t / ntn) * 32;
        for (int i = 0; i < 32; i += 8) {
            int k = kb + threadIdx.y + i, n = nb + threadIdx.x;
            tile[threadIdx.y + i][threadIdx.x] = W[(size_t)k * N + n];
        }
        __syncthreads();
        for (int i = 0; i < 32; i += 8) {
            int n = nb + threadIdx.y + i, k = koff + kb + threadIdx.x;
            size_t o = (size_t)(n >> 7) * ((size_t)KT * 128) + (size_t)(k >> 3) * 1024 +
                       (size_t)((n & 127) * 8) + (k & 7);
            Wt[o] = (__bf16)tile[threadIdx.x][threadIdx.y + i];
        }
    } else if (b < 4804) {                // ---- x -> bf16 ----
        int node = (b - 2304) * 8 + (tid >> 5);   // 8 nodes/block -> whole 64B lines
        int f0 = (tid & 31) * 8;
        float4 u = *(const float4*)(x + (size_t)node * 256 + f0);
        float4 w = *(const float4*)(x + (size_t)node * 256 + f0 + 4);
        alignas(16) __bf16 tmp[8] = {(__bf16)u.x, (__bf16)u.y, (__bf16)u.z, (__bf16)u.w,
                                     (__bf16)w.x, (__bf16)w.y, (__bf16)w.z, (__bf16)w.w};
        *(uint4*)(xrm + (size_t)node * 256 + f0) = *(const uint4*)tmp;
        *(uint4*)(acat + (size_t)(node >> 7) * (512 * 128) +
                  (size_t)(32 + (f0 >> 3)) * 1024 + (size_t)((node & 127) * 8)) =
            *(const uint4*)tmp;
    } else {                              // ---- edge count ----
        int e = (b - 4804) * 256 + tid;   // exactly covers E = 320000
        atomicAdd(&cnt[clampi(ei[N_EDGES + e], 0, N_NODES - 1)], 1);
    }
}

// ---------------- parallel scan (3 kernels, 20 blocks) ----------------

__global__ __launch_bounds__(1024) void k_scan_block(const int* __restrict__ cnt,
                                                     int* __restrict__ off,
                                                     int* __restrict__ bsum, int n) {
    __shared__ int sm[1024];
    int b = blockIdx.x, tid = threadIdx.x;
    int i = b * 1024 + tid;
    int v = (i < n) ? cnt[i] : 0;
    sm[tid] = v;
    __syncthreads();
    for (int s = 1; s < 1024; s <<= 1) {
        int t = (tid >= s) ? sm[tid - s] : 0;
        __syncthreads();
        sm[tid] += t;
        __syncthreads();
    }
    if (i < n) off[i] = sm[tid] - v;
    if (tid == 1023) bsum[b] = sm[1023];
}

__global__ void k_scan_carry(const int* __restrict__ bsum, int* __restrict__ carry,
                             int nb, int* __restrict__ off, int n) {
    if (threadIdx.x == 0 && blockIdx.x == 0) {
        int acc = 0;
        for (int b = 0; b < nb; ++b) { carry[b] = acc; acc += bsum[b]; }
        off[n] = acc;
    }
}

__global__ __launch_bounds__(1024) void k_scan_add(int* __restrict__ off,
                                                   int* __restrict__ cur,
                                                   const int* __restrict__ carry, int n) {
    int i = blockIdx.x * 1024 + threadIdx.x;
    if (i < n) {
        int v = off[i] + carry[blockIdx.x];
        off[i] = v;
        cur[i] = v;
    }
}

__global__ void k_fill(const int* __restrict__ ei, int E,
                       int* __restrict__ cur, int* __restrict__ csr) {
    int e = blockIdx.x * blockDim.x + threadIdx.x;
    if (e < E) {
        int dst = clampi(ei[E + e], 0, N_NODES - 1);
        int src = clampi(ei[e], 0, N_NODES - 1);
        int pos = atomicAdd(&cur[dst], 1);
        if (pos >= 0 && pos < E) csr[pos] = src;
    }
}

// ---------------- aggregation (CSR gather, mean) ----------------
// Wave-per-node; lanes partition features (no LDS / no sync).
// D = row width in bf16 (256 for layer 1, 512 for layers 2/3).
// KC = swizzled Acat K width. Mean goes to chunks 0..D/8-1.
// Unroll-4 with hoisted loads: 4 gather rows in flight per wave.

template <int D, int KC>
__global__ __launch_bounds__(256) void k_agg(const __hip_bfloat16* __restrict__ hrm,
                                             const int* __restrict__ off,
                                             const int* __restrict__ csr,
                                             __bf16* __restrict__ acat) {
    constexpr int FPL = D / 64;   // features per lane: 4 (8B ld) or 8 (16B ld)
    int wave = threadIdx.x >> 6, lane = threadIdx.x & 63;
    int node = blockIdx.x * 4 + wave;
    int c0 = lane * FPL;
    int beg = off[node], end = off[node + 1];
    float a[FPL] = {};

    if constexpr (FPL == 8) {
        auto ldrow = [&](int s) { return *(const uint4*)(hrm + (size_t)s * D + c0); };
        auto addv = [&](uint4 v) {
            const __hip_bfloat16* hb = (const __hip_bfloat16*)&v;
#pragma unroll
            for (int j = 0; j < 8; ++j) a[j] += __bfloat162float(hb[j]);
        };
        int e = beg;
        for (; e + 3 < end; e += 4) {
            int s0 = csr[e], s1 = csr[e + 1], s2 = csr[e + 2], s3 = csr[e + 3];
            uint4 v0 = ldrow(s0), v1 = ldrow(s1), v2 = ldrow(s2), v3 = ldrow(s3);
            addv(v0); addv(v1); addv(v2); addv(v3);
        }
        for (; e < end; ++e) addv(ldrow(csr[e]));
    } else {
        auto ldrow = [&](int s) { return *(const uint2*)(hrm + (size_t)s * D + c0); };
        auto addv = [&](uint2 v) {
            const __hip_bfloat16* hb = (const __hip_bfloat16*)&v;
#pragma unroll
            for (int j = 0; j < 4; ++j) a[j] += __bfloat162float(hb[j]);
        };
        int e = beg;
        for (; e + 3 < end; e += 4) {
            int s0 = csr[e], s1 = csr[e + 1], s2 = csr[e + 2], s3 = csr[e + 3];
            uint2 v0 = ldrow(s0), v1 = ldrow(s1), v2 = ldrow(s2), v3 = ldrow(s3);
            addv(v0); addv(v1); addv(v2); addv(v3);
        }
        for (; e < end; ++e) addv(ldrow(csr[e]));
    }

    float inv = 1.f / fmaxf((float)(end - beg), 1.f);
    alignas(16) __bf16 tmp[FPL];
#pragma unroll
    for (int j = 0; j < FPL; ++j) tmp[j] = (__bf16)(a[j] * inv);

    __bf16* base = acat + (size_t)(node >> 7) * ((size_t)KC * 128) +
                   (size_t)((node & 127) * 8);
    if constexpr (FPL == 8) {
        *(uint4*)(base + (size_t)lane * 1024) = *(const uint4*)tmp;
    } else {
        *(uint2*)(base + (size_t)(lane >> 1) * 1024 + (size_t)((lane & 1) * 4)) =
            *(const uint2*)tmp;
    }
}

// ---------------- bf16 MFMA GEMM, swizzled operands, double-buffered ----------------
// MT = row-tile height (64 or 128). OUTMODE: 0 = bf16 swizzled;
// 1 = bf16 swizzled + row-major copy; 2 = fp32 row-major.

template <bool RELU, int OUTMODE, int MT>
__global__ __launch_bounds__(256) void k_gemm(const __bf16* __restrict__ A, int K, int M,
                                              const __bf16* __restrict__ B,
                                              const float* __restrict__ bias,
                                              __bf16* __restrict__ osw, int Kc, int coff,
                                              __bf16* __restrict__ orm, int ldrm,
                                              float* __restrict__ of32, int ldf,
                                              int rtiles, int ctlog2) {
    constexpr int MREP = MT / 32;             // acc row-fragments per wave
    constexpr int STAGE = MT * 128 + 16384;   // bytes: A (MT*128) + B (16K)
    __shared__ char smem[2 * STAGE];

    int bid = blockIdx.x;
    int xcd = bid & 7, local = bid >> 3;
    int cmask = (1 << ctlog2) - 1;
    int colTile = local & cmask;
    int rowTile = (local >> ctlog2) * 8 + xcd;
    if (rowTile >= rtiles) return;

    int panel = (MT == 128) ? rowTile : (rowTile >> 1);
    int half  = (MT == 128) ? 0 : (rowTile & 1);

    const __bf16* Abase = A + (size_t)panel * ((size_t)K * 128) + half * 512;
    const __bf16* Btile = B + (size_t)colTile * ((size_t)K * 128);

    int tid = threadIdx.x;
    int wave = tid >> 6, lane = tid & 63;
    int wr = wave >> 1, wc = wave & 1;
    int quad = lane >> 4, l16 = lane & 15;

    f32x4 acc[MREP][4] = {};
    const int nt = K >> 6;

    auto stage = [&](int buf, int t) {
        __bf16* Al = (__bf16*)(smem + buf * STAGE);
        __bf16* Bl = (__bf16*)(smem + buf * STAGE + MT * 128);
        // A: MT*8 slots of 16B; k-chunk c is a contiguous MT-slot block at
        // global (t*8+c)*1024 + half*512 (half-panel of the 128-row swizzle).
#pragma unroll
        for (int j = 0; j < MT / 32; ++j) {
            int s = j * 256 + tid;
            int c = s / MT, w = s % MT;
            load16_lds(Abase + (size_t)(t * 8 + c) * 1024 + w * 8, Al + s * 8);
        }
        const __bf16* gB = Btile + (size_t)t * 64 * 128;   // contiguous 16 KB
#pragma unroll
        for (int j = 0; j < 4; ++j) {
            int slot = (j * 256 + tid) * 8;
            load16_lds(gB + slot, Bl + slot);
        }
    };

    stage(0, 0);
    __syncthreads();   // vmcnt(0) drain: buf0 ready
    int cur = 0;
    for (int t = 0; t < nt; ++t) {
        if (t + 1 < nt) stage(cur ^ 1, t + 1);   // prefetch overlaps compute
        const __bf16* Al = (const __bf16*)(smem + cur * STAGE);
        const __bf16* Bl = (const __bf16*)(smem + cur * STAGE + MT * 128);
#pragma unroll
        for (int sp = 0; sp < 2; ++sp) {
            bf16x8 af[MREP], bf[4];
#pragma unroll
            for (int mi = 0; mi < MREP; ++mi)
                af[mi] = *(const bf16x8*)(Al + (sp * 4 + quad) * (MT * 8) +
                                          (wr * (MT / 2) + mi * 16 + l16) * 8);
#pragma unroll
            for (int ni = 0; ni < 4; ++ni)
                bf[ni] = *(const bf16x8*)(Bl + sp * 4096 + quad * 1024 +
                                          (wc * 64 + ni * 16 + l16) * 8);
#pragma unroll
            for (int mi = 0; mi < MREP; ++mi)
#pragma unroll
                for (int ni = 0; ni < 4; ++ni)
                    acc[mi][ni] = __builtin_amdgcn_mfma_f32_16x16x32_bf16(
                        af[mi], bf[ni], acc[mi][ni], 0, 0, 0);
        }
        __syncthreads();   // single barrier/K-step: drains next-tile loads
        cur ^= 1;
    }

    int col0 = colTile * 128;
    int row0 = rowTile * MT;
    // last loop iteration ended with __syncthreads(): smem free for epilogue

    if (OUTMODE != 2) {
        // stage C chunk-major [16 chunks][MT rows][8]
        __bf16* cb = (__bf16*)smem;
#pragma unroll
        for (int ni = 0; ni < 4; ++ni) {
            int ct = wc * 64 + ni * 16 + l16;
            float bv = bias[col0 + ct];
#pragma unroll
            for (int mi = 0; mi < MREP; ++mi) {
                int rb = wr * (MT / 2) + mi * 16 + quad * 4;
#pragma unroll
                for (int r = 0; r < 4; ++r) {
                    float v = acc[mi][ni][r] + bv;
                    if (RELU) v = fmaxf(v, 0.f);
                    cb[(ct >> 3) * (MT * 8) + (rb + r) * 8 + (ct & 7)] = (__bf16)v;
                }
            }
        }
        __syncthreads();
        // swizzled store: 16 chunks of MT slots at 1024-elem stride (half-panel)
        __bf16* dst = osw + (size_t)panel * ((size_t)Kc * 128) +
                      (size_t)((coff + col0) >> 3) * 1024 + half * 512;
#pragma unroll
        for (int p2 = 0; p2 < MT / 16; ++p2) {
            int s = p2 * 256 + tid;
            int cc = s / MT, w = s % MT;
            *(uint4*)(dst + (size_t)cc * 1024 + w * 8) = *(const uint4*)(cb + s * 8);
        }
        if (OUTMODE == 1) {
            // row-major copy for the aggregation gather (padded rows -> no guard)
#pragma unroll
            for (int p2 = 0; p2 < MT / 16; ++p2) {
                int rr = p2 * 16 + (tid >> 4);
                int cc = tid & 15;
                *(uint4*)(orm + (size_t)(row0 + rr) * ldrm + col0 + cc * 8) =
                    *(const uint4*)(cb + cc * (MT * 8) + rr * 8);
            }
        }
    } else {
        float* cf = (float*)smem;   // [MT][68] fp32, two 64-col halves
#pragma unroll
        for (int h = 0; h < 2; ++h) {
            if (wc == h) {
#pragma unroll
                for (int ni = 0; ni < 4; ++ni) {
                    int ctl = ni * 16 + l16;
                    float bv = bias[col0 + h * 64 + ctl];
#pragma unroll
                    for (int mi = 0; mi < MREP; ++mi) {
                        int rb = wr * (MT / 2) + mi * 16 + quad * 4;
#pragma unroll
                        for (int r = 0; r < 4; ++r) {
                            float v = acc[mi][ni][r] + bv;
                            if (RELU) v = fmaxf(v, 0.f);
                            cf[(rb + r) * 68 + ctl] = v;
                        }
                    }
                }
            }
            __syncthreads();
            int chunk = tid & 15, rl = tid >> 4;
#pragma unroll
            for (int p2 = 0; p2 < MT / 16; ++p2) {
                int rt = p2 * 16 + rl;
                int row = row0 + rt;
                if (row < M) {
                    float4 v = *(const float4*)(cf + rt * 68 + chunk * 4);
                    *(float4*)(of32 + (size_t)row * ldf + col0 + h * 64 + chunk * 4) = v;
                }
            }
            __syncthreads();
        }
    }
}

// ---------------- launch ----------------

extern "C" void kernel_launch(void* const* d_in, const int* in_sizes, int n_in,
                              void* d_out, int out_size, void* d_ws, size_t ws_size,
                              hipStream_t stream) {
    const float* x   = (const float*)d_in[0];
    const int*   ei  = (const int*)d_in[1];
    const float* Wl1 = (const float*)d_in[2];
    const float* bl1 = (const float*)d_in[3];
    const float* Wr1 = (const float*)d_in[4];
    const float* Wl2 = (const float*)d_in[5];
    const float* bl2 = (const float*)d_in[6];
    const float* Wr2 = (const float*)d_in[7];
    const float* Wl3 = (const float*)d_in[8];
    const float* bl3 = (const float*)d_in[9];
    const float* Wr3 = (const float*)d_in[10];
    const float* Wfc = (const float*)d_in[11];
    const float* bfc = (const float*)d_in[12];
    float* out = (float*)d_out;

    const int NN = N_NODES, E = N_EDGES;
    const int NB = (NN + 1023) / 1024;

    char* p = (char*)d_ws;
    auto alloc = [&](size_t bytes) {
        char* r = p;
        p += (bytes + 511) & ~(size_t)511;
        return r;
    };
    int* cnt   = (int*)alloc((size_t)NN * 4);
    int* off   = (int*)alloc((size_t)(NN + 1) * 4);
    int* cur   = (int*)alloc((size_t)NN * 4);
    int* csr   = (int*)alloc((size_t)E * 4);
    int* bsum  = (int*)alloc((size_t)NB * 4);
    int* carry = (int*)alloc((size_t)NB * 4);
    __bf16* Acat1 = (__bf16*)alloc((size_t)MPAD * 512 * 2);    // swz [mean|x], K=512
    __bf16* Acat2 = (__bf16*)alloc((size_t)MPAD * 1024 * 2);   // swz [mean|h1], K=1024
    __bf16* Acat3 = (__bf16*)alloc((size_t)MPAD * 1024 * 2);   // swz [mean|h2], K=1024
    __bf16* Hrm   = (__bf16*)alloc((size_t)MPAD * 512 * 2);    // row-major h1, then h2
    __bf16* Xrm   = (__bf16*)alloc((size_t)MPAD * 256 * 2);    // row-major bf16 x
    __bf16* Wt1 = (__bf16*)alloc((size_t)512 * 512 * 2);
    __bf16* Wt2 = (__bf16*)alloc((size_t)512 * 1024 * 2);
    __bf16* Wt3 = (__bf16*)alloc((size_t)1024 * 1024 * 2);
    __bf16* Wt4 = (__bf16*)alloc((size_t)512 * 1024 * 2);
    __bf16* H3 = Acat2;   // alias: Acat2 dead after GEMM2 reads it

    // prep: weight transposes + x->bf16 + edge count (after cnt zeroing)
    hipMemsetAsync(cnt, 0, (size_t)NN * 4, stream);
    TDescs td;
    td.d[0] = {Wl1, Wt1, 256, 512, 512, 0, 0};
    td.d[1] = {Wr1, Wt1, 256, 512, 512, 256, 128};
    td.d[2] = {Wl2, Wt2, 512, 512, 1024, 0, 256};
    td.d[3] = {Wr2, Wt2, 512, 512, 1024, 512, 512};
    td.d[4] = {Wl3, Wt3, 512, 1024, 1024, 0, 768};
    td.d[5] = {Wr3, Wt3, 512, 1024, 1024, 512, 1280};
    td.d[6] = {Wfc, Wt4, 1024, 512, 1024, 0, 1792};
    k_prep<<<6054, dim3(32, 8), 0, stream>>>(td, x, Xrm, Acat1, ei, cnt);

    // parallel scan + CSR fill
    k_scan_block<<<NB, 1024, 0, stream>>>(cnt, off, bsum, NN);
    k_scan_carry<<<1, 64, 0, stream>>>(bsum, carry, NB, off, NN);
    k_scan_add<<<NB, 1024, 0, stream>>>(off, cur, carry, NN);
    k_fill<<<(E + 255) / 256, 256, 0, stream>>>(ei, E, cur, csr);

    int rt128 = (NN + 127) / 128;            // 157
    int rg128 = ((rt128 + 7) / 8) * 8;       // 160
    int rt64  = (NN + 63) / 64;              // 313 -> tiles cover MPAD: use 314
    rt64 = MPAD / 64;                        // 314
    int rg64  = ((rt64 + 7) / 8) * 8;        // 320

    // Layer 1 (bf16 gather @ 512 B/row); N=512 GEMMs use MT=64 (1280 blocks)
    k_agg<256, 512><<<NN / 4, 256, 0, stream>>>(
        (const __hip_bfloat16*)Xrm, off, csr, Acat1);
    k_gemm<true, 1, 64><<<rg64 * 4, 256, 0, stream>>>(
        Acat1, 512, NN, Wt1, bl1, Acat2, 1024, 512, Hrm, 512, nullptr, 0, rt64, 2);

    // Layer 2
    k_agg<512, 1024><<<NN / 4, 256, 0, stream>>>(
        (const __hip_bfloat16*)Hrm, off, csr, Acat2);
    k_gemm<true, 1, 64><<<rg64 * 4, 256, 0, stream>>>(
        Acat2, 1024, NN, Wt2, bl2, Acat3, 1024, 512, Hrm, 512, nullptr, 0, rt64, 2);

    // Layer 3 (N=1024: MT=128, already 1280 blocks; writes H3 swizzled only)
    k_agg<512, 1024><<<NN / 4, 256, 0, stream>>>(
        (const __hip_bfloat16*)Hrm, off, csr, Acat3);
    k_gemm<true, 0, 128><<<rg128 * 8, 256, 0, stream>>>(
        Acat3, 1024, NN, Wt3, bl3, H3, 1024, 0, nullptr, 0, nullptr, 0, rt128, 3);

    // FC (fp32 row-major out, no relu)
    k_gemm<false, 2, 64><<<rg64 * 4, 256, 0, stream>>>(
        H3, 1024, NN, Wt4, bfc, nullptr, 0, 0, nullptr, 0, out, 512, rt64, 2);
}